// Round 14
// baseline (737.388 us; speedup 1.0000x reference)
//
#include <hip/hip_runtime.h>
#include <hip/hip_bf16.h>
#include <stdint.h>

#define NB 32
#define NL 512
#define ND 512

typedef __bf16 bf16x8 __attribute__((ext_vector_type(8)));
typedef float  f32x4  __attribute__((ext_vector_type(4)));

__device__ __forceinline__ unsigned short f2bf(float f) {
    uint32_t u = __float_as_uint(f);
    u = (u + 0x7fffu + ((u >> 16) & 1u)) >> 16;
    return (unsigned short)u;
}

// ============================================================================
// FAST PATH  (round-10 structure + 4 blocks/CU via __launch_bounds__(512,8))
// X' layout (per batch): [kk=l>>5][db=d>>4] subtiles of 512 bf16:
//   subtile chunk c=0..63 (16B) holds (k=(c>>4)*8+j, n=c&15): X[l=kk*32+k][d=db*16+n]
// matching the mfma_f32_16x16x32_bf16 A/B lane layout. Gaussian weights P are
// generated cooperatively into LDS; MFMA uses UNNORMALIZED p_u; dinv applied
// in epilogue. wout = p_u * dinv written in-loop (overlaps MFMA).
// fusedwg5: X fragments loaded GLOBAL->REG; lgkm-only barrier; static
// XCD-partitioned block mapping (r12 proved removing it costs 190 MB HBM).
// (512,8): VGPR=64 fits exactly; LDS 4x39.4KB=157.7KB fits; 4 blocks/CU
// doubles store-issue contexts for this store-drain-bound kernel.
// ============================================================================

// ---- Stage 1: fused convs -> X' bf16 (fragment layout) + ranges ----
__global__ __launch_bounds__(256) void fuse2_kernel(
    const float* __restrict__ x, const float* __restrict__ df,
    const float* __restrict__ en, const float* __restrict__ pi,
    const int* __restrict__ lens,
    const float* __restrict__ w_dur, const float* __restrict__ b_dur,
    const float* __restrict__ w_en,  const float* __restrict__ b_en,
    const float* __restrict__ w_pi,  const float* __restrict__ b_pi,
    const float* __restrict__ w_lin, const float* __restrict__ b_lin,
    unsigned short* __restrict__ Xb, float* __restrict__ ranges)
{
    const int blk = blockIdx.x;          // B * 64
    const int b   = blk >> 6;
    const int lb  = (blk & 63) << 3;     // 8 consecutive l
    const int tid = threadIdx.x;
    const int d0  = tid << 1;            // 2 consecutive d

    float we[2][3], wp[2][3], wd[2][3], bev[2], bpv[2], bdv[2], wl[2];
    #pragma unroll
    for (int q = 0; q < 2; ++q) {
        const int d = d0 + q;
        #pragma unroll
        for (int k = 0; k < 3; ++k) {
            we[q][k] = w_en[d*3+k];
            wp[q][k] = w_pi[d*3+k];
            wd[q][k] = w_dur[d*3+k];
        }
        bev[q] = b_en[d]; bpv[q] = b_pi[d]; bdv[q] = b_dur[d]; wl[q] = w_lin[d];
    }

    float acc[8];
    #pragma unroll
    for (int i = 0; i < 8; ++i) acc[i] = 0.f;

    uint4 chunk[2];
    unsigned short* cu = (unsigned short*)chunk;

    #pragma unroll
    for (int li = 0; li < 8; ++li) {
        const int l  = lb + li;
        const int bl = (b << 9) + l;
        const float dm1 = (l > 0)      ? df[bl-1] : 0.f;
        const float dc  = df[bl];
        const float dp1 = (l < NL-1)   ? df[bl+1] : 0.f;
        const float em1 = (l > 0)      ? en[bl-1] : 0.f;
        const float ec  = en[bl];
        const float ep1 = (l < NL-1)   ? en[bl+1] : 0.f;
        const float pm1 = (l > 0)      ? pi[bl-1] : 0.f;
        const float pc  = pi[bl];
        const float pp1 = (l < NL-1)   ? pi[bl+1] : 0.f;
        const float2 xv = *(const float2*)&x[(size_t)bl * ND + d0];
        #pragma unroll
        for (int q = 0; q < 2; ++q) {
            const float ev  = we[q][0]*em1 + we[q][1]*ec + we[q][2]*ep1 + bev[q];
            const float pv  = wp[q][0]*pm1 + wp[q][1]*pc + wp[q][2]*pp1 + bpv[q];
            const float xxv = (q ? xv.y : xv.x) + ev + pv;
            cu[q*8 + li] = f2bf(xxv);
            const float dv  = wd[q][0]*dm1 + wd[q][1]*dc + wd[q][2]*dp1 + bdv[q];
            acc[li] += (xxv + dv) * wl[q];
        }
    }
    #pragma unroll
    for (int q = 0; q < 2; ++q) {
        const int d = d0 + q;
        const size_t off = (size_t)b * (NL * ND)
            + (size_t)(((lb >> 5) << 5) + (d >> 4)) * 512
            + (size_t)((((lb >> 3) & 3) << 4) + (d & 15)) * 8;
        *(uint4*)&Xb[off] = chunk[q];
    }

    #pragma unroll
    for (int li = 0; li < 8; ++li)
        #pragma unroll
        for (int off = 32; off; off >>= 1)
            acc[li] += __shfl_down(acc[li], off, 64);
    __shared__ float red[4][8];
    const int lane = tid & 63, wid = tid >> 6;
    if (lane == 0)
        #pragma unroll
        for (int li = 0; li < 8; ++li) red[wid][li] = acc[li];
    __syncthreads();
    if (tid < 8) {
        const float s = red[0][tid] + red[1][tid] + red[2][tid] + red[3][tid] + b_lin[0];
        float r = fmaxf(s, 0.f) + log1pf(expf(-fabsf(s)));
        if (lb + tid >= lens[b]) r = 1.0f;
        ranges[(b << 9) + lb + tid] = r;
    }
}

// ---- Stage 2: fused weights + GEMM, 64-t tiles, X in registers ----
// hw block i: xcd=i&7, slot=i>>3, b = xcd*4 + (slot&3), m = slot>>2.
// LDS map (39424 B):
//   [0, 33024)      epilogue bounce (16 rows x 516 f32); ldsP[2][4096] @ [0,8192)
//                   (prologue: scanA@0, scanB@2048, partial@4096 - all dead
//                    before GENP(0,0)/GENP(1,1) overwrite them)
//   [33024, 35072)  t_a[512]   = sinv * sqrt(log2e/2)
//   [35072, 37120)  t_b[512]   = -mu * sinv * sqrt(log2e/2)
//   [37120, 39168)  t_sc[512]  = 0.39894 * sinv (masked)
//   [39168, 39424)  dinvL[64]

#define C2F 0.84932180028801904272f   // sqrt(log2(e)/2)

#define GENP5(kk, buf) do {                                                     \
    const int l0_ = (kk) * 32 + oct * 4;                                        \
    float pv_[4];                                                               \
    unsigned short pu_[4];                                                      \
    _Pragma("unroll")                                                           \
    for (int j = 0; j < 4; ++j) {                                               \
        const float u_ = fmaf(ftv, t_a[l0_ + j], t_b[l0_ + j]);                 \
        pv_[j] = t_sc[l0_ + j] * exp2f(-u_ * u_);                               \
        pu_[j] = f2bf(pv_[j]);                                                  \
    }                                                                           \
    char* pd_ = smem + (buf) * 4096 + (tloc >> 4) * 1024                        \
              + (((oct >> 1) << 4) + (tloc & 15)) * 16 + ((oct & 1) << 3);      \
    *(uint2*)pd_ = *(uint2*)pu_;                                                \
    if (tvalid) {                                                               \
        _Pragma("unroll")                                                       \
        for (int j = 0; j < 4; ++j)                                             \
            woutb[(size_t)(l0_ + j) * T] = pv_[j] * myDinv;                     \
    }                                                                           \
} while (0)

__global__ __launch_bounds__(512, 8) void fusedwg5_kernel(
    const unsigned short* __restrict__ Xb,
    const float* __restrict__ ranges, const int* __restrict__ di,
    const int* __restrict__ lens,
    float* __restrict__ wout, float* __restrict__ xup, int T)
{
    __shared__ __align__(16) char smem[39424];
    float* t_a   = (float*)(smem + 33024);
    float* t_b   = (float*)(smem + 35072);
    float* t_sc  = (float*)(smem + 37120);
    float* dinvL = (float*)(smem + 39168);
    int*   scanA = (int*)smem;             // prologue-only aliases in ldsP area
    int*   scanB = (int*)(smem + 2048);
    float* partial = (float*)(smem + 4096);

    const int tid  = threadIdx.x;
    const int lane = tid & 63, wid = tid >> 6;      // 8 waves
    const int wn   = wid;                           // 1m x 8n

    const int i    = blockIdx.x;
    const int xcd  = i & 7, slot = i >> 3;
    const int b    = (xcd << 2) + (slot & 3);
    const int m    = slot >> 2;                     // 64-t tile
    const int m64  = m << 6;

    const int tloc = tid & 63;
    const int oct  = tid >> 6;                      // 0..7 == wid
    const int tglb = m64 + tloc;
    const bool tvalid = tglb < T;
    const float ftv = (float)tglb + 0.5f;

    const char* Bbase = (const char*)Xb + (size_t)b * (NL * ND * 2)
                      + (size_t)(wn << 2) * 1024 + lane * 16;

    // issue first X-fragment loads at entry; latency hides under prologue
    bf16x8 bxc[4], bxn[4];
    #pragma unroll
    for (int jj = 0; jj < 4; ++jj)
        bxc[jj] = *(const bf16x8*)(Bbase + jj * 1024);

    // ---- prologue: duration scan -> tables ----
    const int dv = di[(b << 9) + tid];
    scanA[tid] = dv;
    __syncthreads();
    {
        int* src = scanA; int* dst = scanB;
        #pragma unroll
        for (int off = 1; off < NL; off <<= 1) {
            dst[tid] = src[tid] + (tid >= off ? src[tid - off] : 0);
            __syncthreads();
            int* tmp = src; src = dst; dst = tmp;
        }
        const float mu = (float)src[tid] - 0.5f * (float)dv;
        const float r  = ranges[(b << 9) + tid];
        const float inv = 1.f / r;
        t_a[tid]  = inv * C2F;
        t_b[tid]  = -mu * inv * C2F;
        t_sc[tid] = (tid < lens[b]) ? 0.3989422804014327f * inv : 0.f;
    }
    __syncthreads();

    // ---- denominator pre-pass: 8 octs x 64 l ----
    {
        float s = 0.f;
        const int lbeg = oct << 6;
        #pragma unroll 4
        for (int l = lbeg; l < lbeg + 64; ++l) {
            const float u = fmaf(ftv, t_a[l], t_b[l]);
            s += t_sc[l] * exp2f(-u * u);
        }
        partial[(oct << 6) + tloc] = s;
    }
    __syncthreads();
    if (tid < 64) {
        float sum = 0.f;
        #pragma unroll
        for (int o = 0; o < 8; ++o) sum += partial[(o << 6) + tid];
        dinvL[tid] = 1.f / (sum + 1e-20f);
    }
    __syncthreads();                      // dinvL ready; scan/partial now dead
    const float myDinv = dinvL[tloc];
    float* woutb = wout + (size_t)(b << 9) * T + tglb;

    f32x4 acc[4][4];
    #pragma unroll
    for (int ii = 0; ii < 4; ++ii)
        #pragma unroll
        for (int jj = 0; jj < 4; ++jj) acc[ii][jj] = (f32x4){0.f, 0.f, 0.f, 0.f};

    GENP5(0, 0);      // overwrites scanA/scanB region (dead) in ldsP buf0

    #pragma unroll
    for (int k = 0; k < 16; ++k) {
        // P-tile barrier: only LDS ordering needed. X-reg readiness is
        // enforced by the compiler's data-dep s_waitcnt before MFMA use.
        asm volatile("s_waitcnt lgkmcnt(0)" ::: "memory");
        __builtin_amdgcn_s_barrier();
        __builtin_amdgcn_sched_barrier(0);
        const int cur = k & 1;
        if (k < 15) {
            #pragma unroll
            for (int jj = 0; jj < 4; ++jj)
                bxn[jj] = *(const bf16x8*)(Bbase + (size_t)(k + 1) * 32768 + jj * 1024);
            GENP5(k + 1, cur ^ 1);
        }
        bf16x8 af[4];
        #pragma unroll
        for (int ii = 0; ii < 4; ++ii)
            af[ii] = *(const bf16x8*)(smem + cur * 4096 + ii * 1024 + lane * 16);
        #pragma unroll
        for (int ii = 0; ii < 4; ++ii)
            #pragma unroll
            for (int jj = 0; jj < 4; ++jj)
                acc[ii][jj] = __builtin_amdgcn_mfma_f32_16x16x32_bf16(af[ii], bxc[jj], acc[ii][jj], 0, 0, 0);
        #pragma unroll
        for (int jj = 0; jj < 4; ++jj) bxc[jj] = bxn[jj];   // SSA rename
    }

    // ---- epilogue: LDS-bounce -> 1KB coalesced xup stores ----
    float* lf = (float*)smem;
    float* Ob = xup + (size_t)b * T * ND;
    #pragma unroll
    for (int c = 0; c < 4; ++c) {
        __syncthreads();
        #pragma unroll
        for (int jj = 0; jj < 4; ++jj)
            #pragma unroll
            for (int r = 0; r < 4; ++r) {
                const int row = ((lane >> 4) << 2) + r;           // 0..15
                const int col = (wn << 6) + (jj << 4) + (lane & 15);
                lf[row * 516 + col] = acc[c][jj][r];
            }
        __syncthreads();
        const int trow = tid >> 7;            // 0..3 (wave-uniform)
        const int colq = (tid & 127) << 2;
        #pragma unroll
        for (int s = 0; s < 4; ++s) {
            const int row = trow + (s << 2);
            const int t = m64 + (c << 4) + row;
            if (t < T) {
                const float dsc = dinvL[(c << 4) + row];
                f32x4 v = *(const f32x4*)(lf + row * 516 + colq);
                v[0] *= dsc; v[1] *= dsc; v[2] *= dsc; v[3] *= dsc;
                *(f32x4*)&Ob[(size_t)t * ND + colq] = v;
            }
        }
    }
}

// ============================================================================
// FALLBACK PATH (round-1 f32, used only if ws_size too small)
// ============================================================================
__global__ __launch_bounds__(512) void means_kernel(
    const int* __restrict__ di, float* __restrict__ means)
{
    const int b = blockIdx.x;
    const int l = threadIdx.x;
    __shared__ int s[NL];
    const int d = di[b * NL + l];
    s[l] = d;
    __syncthreads();
    #pragma unroll
    for (int off = 1; off < NL; off <<= 1) {
        const int v = (l >= off) ? s[l - off] : 0;
        __syncthreads();
        s[l] += v;
        __syncthreads();
    }
    means[b * NL + l] = 0.5f * (float)d + (float)(s[l] - d);
}

__global__ __launch_bounds__(256) void fuse_kernel(
    const float* __restrict__ x, const float* __restrict__ df,
    const float* __restrict__ en, const float* __restrict__ pi,
    const int* __restrict__ lens,
    const float* __restrict__ w_dur, const float* __restrict__ b_dur,
    const float* __restrict__ w_en,  const float* __restrict__ b_en,
    const float* __restrict__ w_pi,  const float* __restrict__ b_pi,
    const float* __restrict__ w_lin, const float* __restrict__ b_lin,
    float* __restrict__ xx, float* __restrict__ ranges)
{
    const int bl = blockIdx.x;
    const int b  = bl >> 9;
    const int l  = bl & (NL - 1);
    const int tid = threadIdx.x;
    const float dm1 = (l > 0)      ? df[bl - 1] : 0.f;
    const float d0  = df[bl];
    const float dp1 = (l < NL - 1) ? df[bl + 1] : 0.f;
    const float em1 = (l > 0)      ? en[bl - 1] : 0.f;
    const float e0  = en[bl];
    const float ep1 = (l < NL - 1) ? en[bl + 1] : 0.f;
    const float pm1 = (l > 0)      ? pi[bl - 1] : 0.f;
    const float p0  = pi[bl];
    const float pp1 = (l < NL - 1) ? pi[bl + 1] : 0.f;
    float acc = 0.f;
    #pragma unroll
    for (int d = tid; d < ND; d += 256) {
        const float xv = x[(size_t)bl * ND + d];
        const float ev = w_en[d*3]*em1 + w_en[d*3+1]*e0 + w_en[d*3+2]*ep1 + b_en[d];
        const float pv = w_pi[d*3]*pm1 + w_pi[d*3+1]*p0 + w_pi[d*3+2]*pp1 + b_pi[d];
        const float xxv = xv + ev + pv;
        xx[(size_t)bl * ND + d] = xxv;
        const float dv = w_dur[d*3]*dm1 + w_dur[d*3+1]*d0 + w_dur[d*3+2]*dp1 + b_dur[d];
        acc += (xxv + dv) * w_lin[d];
    }
    #pragma unroll
    for (int off = 32; off; off >>= 1) acc += __shfl_down(acc, off, 64);
    __shared__ float red[4];
    const int lane = tid & 63, wid = tid >> 6;
    if (lane == 0) red[wid] = acc;
    __syncthreads();
    if (tid == 0) {
        const float s = red[0] + red[1] + red[2] + red[3] + b_lin[0];
        float r = fmaxf(s, 0.f) + log1pf(expf(-fabsf(s)));
        if (l >= lens[b]) r = 1.0f;
        ranges[bl] = r;
    }
}

__global__ __launch_bounds__(256) void weights_kernel(
    const float* __restrict__ ranges, const float* __restrict__ means,
    const int* __restrict__ lens, float* __restrict__ weights, int T)
{
    const int b = blockIdx.y;
    const int t = blockIdx.x * 256 + threadIdx.x;
    __shared__ float sm[NL], sinv[NL], sc[NL];
    const int len = lens[b];
    for (int l = threadIdx.x; l < NL; l += 256) {
        const float r = ranges[b * NL + l];
        const float inv = 1.f / r;
        sm[l] = means[b * NL + l];
        sinv[l] = inv;
        sc[l] = (l < len) ? 0.3989422804014327f * inv : 0.f;
    }
    __syncthreads();
    if (t >= T) return;
    const float ft = (float)t + 0.5f;
    float sum = 0.f;
    #pragma unroll 4
    for (int l = 0; l < NL; ++l) {
        const float z = (ft - sm[l]) * sinv[l];
        sum += sc[l] * __expf(-0.5f * z * z);
    }
    const float dinv = 1.f / (sum + 1e-20f);
    #pragma unroll 4
    for (int l = 0; l < NL; ++l) {
        const float z = (ft - sm[l]) * sinv[l];
        weights[((size_t)b * NL + l) * T + t] = sc[l] * __expf(-0.5f * z * z) * dinv;
    }
}

#define BM 64
#define BN 64
#define BK 16
__global__ __launch_bounds__(256) void gemm_f32_kernel(
    const float* __restrict__ xx, const float* __restrict__ weights,
    float* __restrict__ out, int T)
{
    const int b  = blockIdx.z;
    const int t0 = blockIdx.y * BM;
    const int d0 = blockIdx.x * BN;
    const float* __restrict__ W = weights + (size_t)b * NL * T;
    const float* __restrict__ X = xx + (size_t)b * NL * ND;
    float* __restrict__ O = out + (size_t)b * T * ND;
    __shared__ float As[BK][BM];
    __shared__ float Bs[BK][BN];
    const int tid = threadIdx.x;
    const int tx = tid & 15;
    const int ty = tid >> 4;
    const int lr = tid >> 4;
    const int lc = (tid & 15) * 4;
    const bool vec_ok = (t0 + BM <= T) && ((T & 3) == 0);
    float acc[4][4] = {};
    for (int l0 = 0; l0 < NL; l0 += BK) {
        if (vec_ok) {
            *(float4*)&As[lr][lc] = *(const float4*)&W[(size_t)(l0 + lr) * T + t0 + lc];
        } else {
            #pragma unroll
            for (int j = 0; j < 4; ++j) {
                const int tcol = t0 + lc + j;
                As[lr][lc + j] = (tcol < T) ? W[(size_t)(l0 + lr) * T + tcol] : 0.f;
            }
        }
        *(float4*)&Bs[lr][lc] = *(const float4*)&X[(size_t)(l0 + lr) * ND + d0 + lc];
        __syncthreads();
        #pragma unroll
        for (int k = 0; k < BK; ++k) {
            float a[4], bb[4];
            *(float4*)a  = *(const float4*)&As[k][ty * 4];
            *(float4*)bb = *(const float4*)&Bs[k][tx * 4];
            #pragma unroll
            for (int i = 0; i < 4; ++i)
                #pragma unroll
                for (int j = 0; j < 4; ++j)
                    acc[i][j] += a[i] * bb[j];
        }
        __syncthreads();
    }
    #pragma unroll
    for (int i = 0; i < 4; ++i) {
        const int t = t0 + ty * 4 + i;
        if (t < T)
            *(float4*)&O[(size_t)t * ND + d0 + tx * 4] =
                make_float4(acc[i][0], acc[i][1], acc[i][2], acc[i][3]);
    }
}

// ============================================================================
extern "C" void kernel_launch(void* const* d_in, const int* in_sizes, int n_in,
                              void* d_out, int out_size, void* d_ws, size_t ws_size,
                              hipStream_t stream) {
    const float* x     = (const float*)d_in[0];
    const float* df    = (const float*)d_in[1];
    const int*   di    = (const int*)  d_in[2];
    const float* en    = (const float*)d_in[3];
    const float* pi    = (const float*)d_in[4];
    const int*   lens  = (const int*)  d_in[5];
    const float* w_dur = (const float*)d_in[6];
    const float* b_dur = (const float*)d_in[7];
    const float* w_en  = (const float*)d_in[8];
    const float* b_en  = (const float*)d_in[9];
    const float* w_pi  = (const float*)d_in[10];
    const float* b_pi  = (const float*)d_in[11];
    const float* w_lin = (const float*)d_in[12];
    const float* b_lin = (const float*)d_in[13];

    const int B = NB, L = NL, D = ND;
    const int T = out_size / (B * (L + D));
    const int MT = (T + 63) / 64;                // # of 64-t tiles

    float* xup  = (float*)d_out;                 // (B,T,D)
    float* wout = xup + (size_t)B * T * D;       // (B,L,T)

    const size_t XbBytes = (size_t)B * L * D * 2;
    const size_t need = XbBytes + (size_t)B * L * sizeof(float);

    if (ws_size >= need) {
        unsigned short* Xb = (unsigned short*)d_ws;
        float* ranges = (float*)(Xb + (size_t)B * L * D);

        hipLaunchKernelGGL(fuse2_kernel, dim3(B * 64), dim3(256), 0, stream,
                           x, df, en, pi, lens, w_dur, b_dur, w_en, b_en,
                           w_pi, b_pi, w_lin, b_lin, Xb, ranges);
        hipLaunchKernelGGL(fusedwg5_kernel, dim3(MT * 32), dim3(512), 0, stream,
                           Xb, ranges, di, lens, wout, xup, T);
    } else {
        float* xx     = (float*)d_ws;
        float* ranges = xx + (size_t)B * L * D;
        float* means  = ranges + (size_t)B * L;
        hipLaunchKernelGGL(fuse_kernel, dim3(B * L), dim3(256), 0, stream,
                           x, df, en, pi, lens, w_dur, b_dur, w_en, b_en,
                           w_pi, b_pi, w_lin, b_lin, xx, ranges);
        hipLaunchKernelGGL(means_kernel, dim3(B), dim3(512), 0, stream, di, means);
        hipLaunchKernelGGL(weights_kernel, dim3((T + 255) / 256, B), dim3(256), 0, stream,
                           ranges, means, lens, wout, T);
        hipLaunchKernelGGL(gemm_f32_kernel, dim3(D / BN, (T + BM - 1) / BM, B), dim3(256), 0, stream,
                           xx, wout, xup, T);
    }
}

// Round 15
// 98.809 us; speedup vs baseline: 7.4627x; 7.4627x over previous
//
#include <hip/hip_runtime.h>
#include <hip/hip_bf16.h>
#include <stdint.h>

#define NB 32
#define NL 512
#define ND 512

typedef __bf16 bf16x8 __attribute__((ext_vector_type(8)));
typedef float  f32x4  __attribute__((ext_vector_type(4)));

__device__ __forceinline__ unsigned short f2bf(float f) {
    uint32_t u = __float_as_uint(f);
    u = (u + 0x7fffu + ((u >> 16) & 1u)) >> 16;
    return (unsigned short)u;
}

// ============================================================================
// FAST PATH  (exact round-13 structure — best measured, 98.9 us)
// X' layout (per batch): [kk=l>>5][db=d>>4] subtiles of 512 bf16:
//   subtile chunk c=0..63 (16B) holds (k=(c>>4)*8+j, n=c&15): X[l=kk*32+k][d=db*16+n]
// matching the mfma_f32_16x16x32_bf16 A/B lane layout. Gaussian weights P are
// generated cooperatively into LDS; MFMA uses UNNORMALIZED p_u; dinv applied
// in epilogue. wout = p_u * dinv written in-loop (overlaps MFMA).
// fusedwg5: X fragments loaded GLOBAL->REG (no X LDS round-trip); lgkm-only
// barrier; static XCD-partitioned block mapping (b pinned per XCD -> Xb panels
// L2-resident; r12 proved removing this costs 190 MB of HBM re-fetch).
// __launch_bounds__(512,4): r14 proved (512,8) forces VGPR 64->32 and spills
// (3 GB scratch traffic, 7.4x slowdown). 2 blocks/CU is the sweet spot.
// ============================================================================

// ---- Stage 1: fused convs -> X' bf16 (fragment layout) + ranges ----
__global__ __launch_bounds__(256) void fuse2_kernel(
    const float* __restrict__ x, const float* __restrict__ df,
    const float* __restrict__ en, const float* __restrict__ pi,
    const int* __restrict__ lens,
    const float* __restrict__ w_dur, const float* __restrict__ b_dur,
    const float* __restrict__ w_en,  const float* __restrict__ b_en,
    const float* __restrict__ w_pi,  const float* __restrict__ b_pi,
    const float* __restrict__ w_lin, const float* __restrict__ b_lin,
    unsigned short* __restrict__ Xb, float* __restrict__ ranges)
{
    const int blk = blockIdx.x;          // B * 64
    const int b   = blk >> 6;
    const int lb  = (blk & 63) << 3;     // 8 consecutive l
    const int tid = threadIdx.x;
    const int d0  = tid << 1;            // 2 consecutive d

    float we[2][3], wp[2][3], wd[2][3], bev[2], bpv[2], bdv[2], wl[2];
    #pragma unroll
    for (int q = 0; q < 2; ++q) {
        const int d = d0 + q;
        #pragma unroll
        for (int k = 0; k < 3; ++k) {
            we[q][k] = w_en[d*3+k];
            wp[q][k] = w_pi[d*3+k];
            wd[q][k] = w_dur[d*3+k];
        }
        bev[q] = b_en[d]; bpv[q] = b_pi[d]; bdv[q] = b_dur[d]; wl[q] = w_lin[d];
    }

    float acc[8];
    #pragma unroll
    for (int i = 0; i < 8; ++i) acc[i] = 0.f;

    uint4 chunk[2];
    unsigned short* cu = (unsigned short*)chunk;

    #pragma unroll
    for (int li = 0; li < 8; ++li) {
        const int l  = lb + li;
        const int bl = (b << 9) + l;
        const float dm1 = (l > 0)      ? df[bl-1] : 0.f;
        const float dc  = df[bl];
        const float dp1 = (l < NL-1)   ? df[bl+1] : 0.f;
        const float em1 = (l > 0)      ? en[bl-1] : 0.f;
        const float ec  = en[bl];
        const float ep1 = (l < NL-1)   ? en[bl+1] : 0.f;
        const float pm1 = (l > 0)      ? pi[bl-1] : 0.f;
        const float pc  = pi[bl];
        const float pp1 = (l < NL-1)   ? pi[bl+1] : 0.f;
        const float2 xv = *(const float2*)&x[(size_t)bl * ND + d0];
        #pragma unroll
        for (int q = 0; q < 2; ++q) {
            const float ev  = we[q][0]*em1 + we[q][1]*ec + we[q][2]*ep1 + bev[q];
            const float pv  = wp[q][0]*pm1 + wp[q][1]*pc + wp[q][2]*pp1 + bpv[q];
            const float xxv = (q ? xv.y : xv.x) + ev + pv;
            cu[q*8 + li] = f2bf(xxv);
            const float dv  = wd[q][0]*dm1 + wd[q][1]*dc + wd[q][2]*dp1 + bdv[q];
            acc[li] += (xxv + dv) * wl[q];
        }
    }
    #pragma unroll
    for (int q = 0; q < 2; ++q) {
        const int d = d0 + q;
        const size_t off = (size_t)b * (NL * ND)
            + (size_t)(((lb >> 5) << 5) + (d >> 4)) * 512
            + (size_t)((((lb >> 3) & 3) << 4) + (d & 15)) * 8;
        *(uint4*)&Xb[off] = chunk[q];
    }

    #pragma unroll
    for (int li = 0; li < 8; ++li)
        #pragma unroll
        for (int off = 32; off; off >>= 1)
            acc[li] += __shfl_down(acc[li], off, 64);
    __shared__ float red[4][8];
    const int lane = tid & 63, wid = tid >> 6;
    if (lane == 0)
        #pragma unroll
        for (int li = 0; li < 8; ++li) red[wid][li] = acc[li];
    __syncthreads();
    if (tid < 8) {
        const float s = red[0][tid] + red[1][tid] + red[2][tid] + red[3][tid] + b_lin[0];
        float r = fmaxf(s, 0.f) + log1pf(expf(-fabsf(s)));
        if (lb + tid >= lens[b]) r = 1.0f;
        ranges[(b << 9) + lb + tid] = r;
    }
}

// ---- Stage 2: fused weights + GEMM, 64-t tiles, X in registers ----
// hw block i: xcd=i&7, slot=i>>3, b = xcd*4 + (slot&3), m = slot>>2.
// LDS map (39424 B):
//   [0, 33024)      epilogue bounce (16 rows x 516 f32); ldsP[2][4096] @ [0,8192)
//                   (prologue: scanA@0, scanB@2048, partial@4096 - all dead
//                    before GENP(0,0)/GENP(1,1) overwrite them)
//   [33024, 35072)  t_a[512]   = sinv * sqrt(log2e/2)
//   [35072, 37120)  t_b[512]   = -mu * sinv * sqrt(log2e/2)
//   [37120, 39168)  t_sc[512]  = 0.39894 * sinv (masked)
//   [39168, 39424)  dinvL[64]

#define C2F 0.84932180028801904272f   // sqrt(log2(e)/2)

#define GENP5(kk, buf) do {                                                     \
    const int l0_ = (kk) * 32 + oct * 4;                                        \
    float pv_[4];                                                               \
    unsigned short pu_[4];                                                      \
    _Pragma("unroll")                                                           \
    for (int j = 0; j < 4; ++j) {                                               \
        const float u_ = fmaf(ftv, t_a[l0_ + j], t_b[l0_ + j]);                 \
        pv_[j] = t_sc[l0_ + j] * exp2f(-u_ * u_);                               \
        pu_[j] = f2bf(pv_[j]);                                                  \
    }                                                                           \
    char* pd_ = smem + (buf) * 4096 + (tloc >> 4) * 1024                        \
              + (((oct >> 1) << 4) + (tloc & 15)) * 16 + ((oct & 1) << 3);      \
    *(uint2*)pd_ = *(uint2*)pu_;                                                \
    if (tvalid) {                                                               \
        _Pragma("unroll")                                                       \
        for (int j = 0; j < 4; ++j)                                             \
            woutb[(size_t)(l0_ + j) * T] = pv_[j] * myDinv;                     \
    }                                                                           \
} while (0)

__global__ __launch_bounds__(512, 4) void fusedwg5_kernel(
    const unsigned short* __restrict__ Xb,
    const float* __restrict__ ranges, const int* __restrict__ di,
    const int* __restrict__ lens,
    float* __restrict__ wout, float* __restrict__ xup, int T)
{
    __shared__ __align__(16) char smem[39424];
    float* t_a   = (float*)(smem + 33024);
    float* t_b   = (float*)(smem + 35072);
    float* t_sc  = (float*)(smem + 37120);
    float* dinvL = (float*)(smem + 39168);
    int*   scanA = (int*)smem;             // prologue-only aliases in ldsP area
    int*   scanB = (int*)(smem + 2048);
    float* partial = (float*)(smem + 4096);

    const int tid  = threadIdx.x;
    const int lane = tid & 63, wid = tid >> 6;      // 8 waves
    const int wn   = wid;                           // 1m x 8n

    const int i    = blockIdx.x;
    const int xcd  = i & 7, slot = i >> 3;
    const int b    = (xcd << 2) + (slot & 3);
    const int m    = slot >> 2;                     // 64-t tile
    const int m64  = m << 6;

    const int tloc = tid & 63;
    const int oct  = tid >> 6;                      // 0..7 == wid
    const int tglb = m64 + tloc;
    const bool tvalid = tglb < T;
    const float ftv = (float)tglb + 0.5f;

    const char* Bbase = (const char*)Xb + (size_t)b * (NL * ND * 2)
                      + (size_t)(wn << 2) * 1024 + lane * 16;

    // issue first X-fragment loads at entry; latency hides under prologue
    bf16x8 bxc[4], bxn[4];
    #pragma unroll
    for (int jj = 0; jj < 4; ++jj)
        bxc[jj] = *(const bf16x8*)(Bbase + jj * 1024);

    // ---- prologue: duration scan -> tables ----
    const int dv = di[(b << 9) + tid];
    scanA[tid] = dv;
    __syncthreads();
    {
        int* src = scanA; int* dst = scanB;
        #pragma unroll
        for (int off = 1; off < NL; off <<= 1) {
            dst[tid] = src[tid] + (tid >= off ? src[tid - off] : 0);
            __syncthreads();
            int* tmp = src; src = dst; dst = tmp;
        }
        const float mu = (float)src[tid] - 0.5f * (float)dv;
        const float r  = ranges[(b << 9) + tid];
        const float inv = 1.f / r;
        t_a[tid]  = inv * C2F;
        t_b[tid]  = -mu * inv * C2F;
        t_sc[tid] = (tid < lens[b]) ? 0.3989422804014327f * inv : 0.f;
    }
    __syncthreads();

    // ---- denominator pre-pass: 8 octs x 64 l ----
    {
        float s = 0.f;
        const int lbeg = oct << 6;
        #pragma unroll 4
        for (int l = lbeg; l < lbeg + 64; ++l) {
            const float u = fmaf(ftv, t_a[l], t_b[l]);
            s += t_sc[l] * exp2f(-u * u);
        }
        partial[(oct << 6) + tloc] = s;
    }
    __syncthreads();
    if (tid < 64) {
        float sum = 0.f;
        #pragma unroll
        for (int o = 0; o < 8; ++o) sum += partial[(o << 6) + tid];
        dinvL[tid] = 1.f / (sum + 1e-20f);
    }
    __syncthreads();                      // dinvL ready; scan/partial now dead
    const float myDinv = dinvL[tloc];
    float* woutb = wout + (size_t)(b << 9) * T + tglb;

    f32x4 acc[4][4];
    #pragma unroll
    for (int ii = 0; ii < 4; ++ii)
        #pragma unroll
        for (int jj = 0; jj < 4; ++jj) acc[ii][jj] = (f32x4){0.f, 0.f, 0.f, 0.f};

    GENP5(0, 0);      // overwrites scanA/scanB region (dead) in ldsP buf0

    #pragma unroll
    for (int k = 0; k < 16; ++k) {
        // P-tile barrier: only LDS ordering needed. X-reg readiness is
        // enforced by the compiler's data-dep s_waitcnt before MFMA use.
        asm volatile("s_waitcnt lgkmcnt(0)" ::: "memory");
        __builtin_amdgcn_s_barrier();
        __builtin_amdgcn_sched_barrier(0);
        const int cur = k & 1;
        if (k < 15) {
            #pragma unroll
            for (int jj = 0; jj < 4; ++jj)
                bxn[jj] = *(const bf16x8*)(Bbase + (size_t)(k + 1) * 32768 + jj * 1024);
            GENP5(k + 1, cur ^ 1);
        }
        bf16x8 af[4];
        #pragma unroll
        for (int ii = 0; ii < 4; ++ii)
            af[ii] = *(const bf16x8*)(smem + cur * 4096 + ii * 1024 + lane * 16);
        #pragma unroll
        for (int ii = 0; ii < 4; ++ii)
            #pragma unroll
            for (int jj = 0; jj < 4; ++jj)
                acc[ii][jj] = __builtin_amdgcn_mfma_f32_16x16x32_bf16(af[ii], bxc[jj], acc[ii][jj], 0, 0, 0);
        #pragma unroll
        for (int jj = 0; jj < 4; ++jj) bxc[jj] = bxn[jj];   // SSA rename
    }

    // ---- epilogue: LDS-bounce -> 1KB coalesced xup stores ----
    float* lf = (float*)smem;
    float* Ob = xup + (size_t)b * T * ND;
    #pragma unroll
    for (int c = 0; c < 4; ++c) {
        __syncthreads();
        #pragma unroll
        for (int jj = 0; jj < 4; ++jj)
            #pragma unroll
            for (int r = 0; r < 4; ++r) {
                const int row = ((lane >> 4) << 2) + r;           // 0..15
                const int col = (wn << 6) + (jj << 4) + (lane & 15);
                lf[row * 516 + col] = acc[c][jj][r];
            }
        __syncthreads();
        const int trow = tid >> 7;            // 0..3 (wave-uniform)
        const int colq = (tid & 127) << 2;
        #pragma unroll
        for (int s = 0; s < 4; ++s) {
            const int row = trow + (s << 2);
            const int t = m64 + (c << 4) + row;
            if (t < T) {
                const float dsc = dinvL[(c << 4) + row];
                f32x4 v = *(const f32x4*)(lf + row * 516 + colq);
                v[0] *= dsc; v[1] *= dsc; v[2] *= dsc; v[3] *= dsc;
                *(f32x4*)&Ob[(size_t)t * ND + colq] = v;
            }
        }
    }
}

// ============================================================================
// FALLBACK PATH (round-1 f32, used only if ws_size too small)
// ============================================================================
__global__ __launch_bounds__(512) void means_kernel(
    const int* __restrict__ di, float* __restrict__ means)
{
    const int b = blockIdx.x;
    const int l = threadIdx.x;
    __shared__ int s[NL];
    const int d = di[b * NL + l];
    s[l] = d;
    __syncthreads();
    #pragma unroll
    for (int off = 1; off < NL; off <<= 1) {
        const int v = (l >= off) ? s[l - off] : 0;
        __syncthreads();
        s[l] += v;
        __syncthreads();
    }
    means[b * NL + l] = 0.5f * (float)d + (float)(s[l] - d);
}

__global__ __launch_bounds__(256) void fuse_kernel(
    const float* __restrict__ x, const float* __restrict__ df,
    const float* __restrict__ en, const float* __restrict__ pi,
    const int* __restrict__ lens,
    const float* __restrict__ w_dur, const float* __restrict__ b_dur,
    const float* __restrict__ w_en,  const float* __restrict__ b_en,
    const float* __restrict__ w_pi,  const float* __restrict__ b_pi,
    const float* __restrict__ w_lin, const float* __restrict__ b_lin,
    float* __restrict__ xx, float* __restrict__ ranges)
{
    const int bl = blockIdx.x;
    const int b  = bl >> 9;
    const int l  = bl & (NL - 1);
    const int tid = threadIdx.x;
    const float dm1 = (l > 0)      ? df[bl - 1] : 0.f;
    const float d0  = df[bl];
    const float dp1 = (l < NL - 1) ? df[bl + 1] : 0.f;
    const float em1 = (l > 0)      ? en[bl - 1] : 0.f;
    const float e0  = en[bl];
    const float ep1 = (l < NL - 1) ? en[bl + 1] : 0.f;
    const float pm1 = (l > 0)      ? pi[bl - 1] : 0.f;
    const float p0  = pi[bl];
    const float pp1 = (l < NL - 1) ? pi[bl + 1] : 0.f;
    float acc = 0.f;
    #pragma unroll
    for (int d = tid; d < ND; d += 256) {
        const float xv = x[(size_t)bl * ND + d];
        const float ev = w_en[d*3]*em1 + w_en[d*3+1]*e0 + w_en[d*3+2]*ep1 + b_en[d];
        const float pv = w_pi[d*3]*pm1 + w_pi[d*3+1]*p0 + w_pi[d*3+2]*pp1 + b_pi[d];
        const float xxv = xv + ev + pv;
        xx[(size_t)bl * ND + d] = xxv;
        const float dv = w_dur[d*3]*dm1 + w_dur[d*3+1]*d0 + w_dur[d*3+2]*dp1 + b_dur[d];
        acc += (xxv + dv) * w_lin[d];
    }
    #pragma unroll
    for (int off = 32; off; off >>= 1) acc += __shfl_down(acc, off, 64);
    __shared__ float red[4];
    const int lane = tid & 63, wid = tid >> 6;
    if (lane == 0) red[wid] = acc;
    __syncthreads();
    if (tid == 0) {
        const float s = red[0] + red[1] + red[2] + red[3] + b_lin[0];
        float r = fmaxf(s, 0.f) + log1pf(expf(-fabsf(s)));
        if (l >= lens[b]) r = 1.0f;
        ranges[bl] = r;
    }
}

__global__ __launch_bounds__(256) void weights_kernel(
    const float* __restrict__ ranges, const float* __restrict__ means,
    const int* __restrict__ lens, float* __restrict__ weights, int T)
{
    const int b = blockIdx.y;
    const int t = blockIdx.x * 256 + threadIdx.x;
    __shared__ float sm[NL], sinv[NL], sc[NL];
    const int len = lens[b];
    for (int l = threadIdx.x; l < NL; l += 256) {
        const float r = ranges[b * NL + l];
        const float inv = 1.f / r;
        sm[l] = means[b * NL + l];
        sinv[l] = inv;
        sc[l] = (l < len) ? 0.3989422804014327f * inv : 0.f;
    }
    __syncthreads();
    if (t >= T) return;
    const float ft = (float)t + 0.5f;
    float sum = 0.f;
    #pragma unroll 4
    for (int l = 0; l < NL; ++l) {
        const float z = (ft - sm[l]) * sinv[l];
        sum += sc[l] * __expf(-0.5f * z * z);
    }
    const float dinv = 1.f / (sum + 1e-20f);
    #pragma unroll 4
    for (int l = 0; l < NL; ++l) {
        const float z = (ft - sm[l]) * sinv[l];
        weights[((size_t)b * NL + l) * T + t] = sc[l] * __expf(-0.5f * z * z) * dinv;
    }
}

#define BM 64
#define BN 64
#define BK 16
__global__ __launch_bounds__(256) void gemm_f32_kernel(
    const float* __restrict__ xx, const float* __restrict__ weights,
    float* __restrict__ out, int T)
{
    const int b  = blockIdx.z;
    const int t0 = blockIdx.y * BM;
    const int d0 = blockIdx.x * BN;
    const float* __restrict__ W = weights + (size_t)b * NL * T;
    const float* __restrict__ X = xx + (size_t)b * NL * ND;
    float* __restrict__ O = out + (size_t)b * T * ND;
    __shared__ float As[BK][BM];
    __shared__ float Bs[BK][BN];
    const int tid = threadIdx.x;
    const int tx = tid & 15;
    const int ty = tid >> 4;
    const int lr = tid >> 4;
    const int lc = (tid & 15) * 4;
    const bool vec_ok = (t0 + BM <= T) && ((T & 3) == 0);
    float acc[4][4] = {};
    for (int l0 = 0; l0 < NL; l0 += BK) {
        if (vec_ok) {
            *(float4*)&As[lr][lc] = *(const float4*)&W[(size_t)(l0 + lr) * T + t0 + lc];
        } else {
            #pragma unroll
            for (int j = 0; j < 4; ++j) {
                const int tcol = t0 + lc + j;
                As[lr][lc + j] = (tcol < T) ? W[(size_t)(l0 + lr) * T + tcol] : 0.f;
            }
        }
        *(float4*)&Bs[lr][lc] = *(const float4*)&X[(size_t)(l0 + lr) * ND + d0 + lc];
        __syncthreads();
        #pragma unroll
        for (int k = 0; k < BK; ++k) {
            float a[4], bb[4];
            *(float4*)a  = *(const float4*)&As[k][ty * 4];
            *(float4*)bb = *(const float4*)&Bs[k][tx * 4];
            #pragma unroll
            for (int i = 0; i < 4; ++i)
                #pragma unroll
                for (int j = 0; j < 4; ++j)
                    acc[i][j] += a[i] * bb[j];
        }
        __syncthreads();
    }
    #pragma unroll
    for (int i = 0; i < 4; ++i) {
        const int t = t0 + ty * 4 + i;
        if (t < T)
            *(float4*)&O[(size_t)t * ND + d0 + tx * 4] =
                make_float4(acc[i][0], acc[i][1], acc[i][2], acc[i][3]);
    }
}

// ============================================================================
extern "C" void kernel_launch(void* const* d_in, const int* in_sizes, int n_in,
                              void* d_out, int out_size, void* d_ws, size_t ws_size,
                              hipStream_t stream) {
    const float* x     = (const float*)d_in[0];
    const float* df    = (const float*)d_in[1];
    const int*   di    = (const int*)  d_in[2];
    const float* en    = (const float*)d_in[3];
    const float* pi    = (const float*)d_in[4];
    const int*   lens  = (const int*)  d_in[5];
    const float* w_dur = (const float*)d_in[6];
    const float* b_dur = (const float*)d_in[7];
    const float* w_en  = (const float*)d_in[8];
    const float* b_en  = (const float*)d_in[9];
    const float* w_pi  = (const float*)d_in[10];
    const float* b_pi  = (const float*)d_in[11];
    const float* w_lin = (const float*)d_in[12];
    const float* b_lin = (const float*)d_in[13];

    const int B = NB, L = NL, D = ND;
    const int T = out_size / (B * (L + D));
    const int MT = (T + 63) / 64;                // # of 64-t tiles

    float* xup  = (float*)d_out;                 // (B,T,D)
    float* wout = xup + (size_t)B * T * D;       // (B,L,T)

    const size_t XbBytes = (size_t)B * L * D * 2;
    const size_t need = XbBytes + (size_t)B * L * sizeof(float);

    if (ws_size >= need) {
        unsigned short* Xb = (unsigned short*)d_ws;
        float* ranges = (float*)(Xb + (size_t)B * L * D);

        hipLaunchKernelGGL(fuse2_kernel, dim3(B * 64), dim3(256), 0, stream,
                           x, df, en, pi, lens, w_dur, b_dur, w_en, b_en,
                           w_pi, b_pi, w_lin, b_lin, Xb, ranges);
        hipLaunchKernelGGL(fusedwg5_kernel, dim3(MT * 32), dim3(512), 0, stream,
                           Xb, ranges, di, lens, wout, xup, T);
    } else {
        float* xx     = (float*)d_ws;
        float* ranges = xx + (size_t)B * L * D;
        float* means  = ranges + (size_t)B * L;
        hipLaunchKernelGGL(fuse_kernel, dim3(B * L), dim3(256), 0, stream,
                           x, df, en, pi, lens, w_dur, b_dur, w_en, b_en,
                           w_pi, b_pi, w_lin, b_lin, xx, ranges);
        hipLaunchKernelGGL(means_kernel, dim3(B), dim3(512), 0, stream, di, means);
        hipLaunchKernelGGL(weights_kernel, dim3((T + 255) / 256, B), dim3(256), 0, stream,
                           ranges, means, lens, wout, T);
        hipLaunchKernelGGL(gemm_f32_kernel, dim3(D / BN, (T + BM - 1) / BM, B), dim3(256), 0, stream,
                           xx, wout, xup, T);
    }
}